// Round 3
// baseline (206.375 us; speedup 1.0000x reference)
//
#include <hip/hip_runtime.h>
#include <hip/hip_bf16.h>

typedef __bf16 bf16x8 __attribute__((ext_vector_type(8)));
typedef float  f32x4  __attribute__((ext_vector_type(4)));

// Sizes: q [1024][128] f32, k [1024][128] f32, queue [128][65536] f32,
//        prototypes [1000][128] f32, target [1024] int32
// Outputs (concat f32): logits [1024][65537], logits_proto [1024][1000],
//        new_queue [128][65536], new_prototypes [1000][128]
// d_ws: Bt = bf16 queue^T [65536][128] (16.8 MB), qbf = bf16(10*q) [1024][128]

#define B_   1024
#define D_   128
#define K_   65536
#define C_   1000
#define LROW 65537
#define TINV 10.0f

// ---- convert_T: read queue once; emit new_queue copy + bf16 transposed Bt ----
// LDS: Lt[c][d] with 16B-block XOR swizzle (block db stored at db ^ ((c>>2)&15))
__global__ __launch_bounds__(256) void convert_T(const float* __restrict__ queue,
                                                 float* __restrict__ outq,
                                                 __bf16* __restrict__ Bt) {
    __shared__ __bf16 Lt[128 * 128];
    char* ltb = (char*)Lt;
    const int tid = threadIdx.x;
    const int c0  = blockIdx.x * 128;
    #pragma unroll
    for (int it = 0; it < 16; ++it) {
        const int idx = it * 256 + tid;          // float4 slot in 128d x 128c tile
        const int d   = idx >> 5;
        const int cq  = (idx & 31) * 4;
        const float4 v = *reinterpret_cast<const float4*>(queue + (size_t)d * K_ + c0 + cq);
        *reinterpret_cast<float4*>(outq + (size_t)d * K_ + c0 + cq) = v;
        const int db = d >> 3, de = (d & 7) * 2;
        float vv[4] = {v.x, v.y, v.z, v.w};
        #pragma unroll
        for (int jj = 0; jj < 4; ++jj) {
            const int c = cq + jj;
            *reinterpret_cast<__bf16*>(ltb + c * 256 + ((db ^ ((c >> 2) & 15)) << 4) + de)
                = (__bf16)vv[jj];
        }
    }
    __syncthreads();
    #pragma unroll
    for (int it = 0; it < 8; ++it) {
        const int idx = it * 256 + tid;          // 16B chunk: c = idx>>4, db = idx&15
        const int c   = idx >> 4;
        const int db  = idx & 15;
        const bf16x8 v = *reinterpret_cast<const bf16x8*>(
            ltb + c * 256 + ((db ^ ((c >> 2) & 15)) << 4));
        *reinterpret_cast<bf16x8*>(Bt + (size_t)(c0 + c) * D_ + db * 8) = v;
    }
}

// ---- l_pos + qbf: logits[:,0] = (q·k)/T ; qbf = bf16(10*q) ----
__global__ __launch_bounds__(256) void lpos_qbf(const float* __restrict__ q,
                                                const float* __restrict__ k,
                                                float* __restrict__ logits,
                                                __bf16* __restrict__ qbf) {
    const int wid  = threadIdx.x >> 6;
    const int lane = threadIdx.x & 63;
    const int row  = blockIdx.x * 4 + wid;
    const float2 qv = reinterpret_cast<const float2*>(q + (size_t)row * D_)[lane];
    const float2 kv = reinterpret_cast<const float2*>(k + (size_t)row * D_)[lane];
    union { __bf16 h[2]; unsigned int u; } t;
    t.h[0] = (__bf16)(qv.x * TINV);
    t.h[1] = (__bf16)(qv.y * TINV);
    reinterpret_cast<unsigned int*>(qbf)[row * 64 + lane] = t.u;
    float p = qv.x * kv.x + qv.y * kv.y;
    #pragma unroll
    for (int off = 32; off > 0; off >>= 1) p += __shfl_xor(p, off);
    if (lane == 0) logits[(size_t)row * LROW] = p * TINV;
}

// ---- big GEMM: logits[:,1:] = qbf @ Bt^T (10/T folded into qbf), LDS-free ----
// XCD-bijective, col-tile-fastest within XCD (adjacent tiles concurrent -> L2 merge)
__global__ __launch_bounds__(256, 3) void gemm_neg(const __bf16* __restrict__ qbf,
                                                   const __bf16* __restrict__ Bt,
                                                   float* __restrict__ logits) {
    const int tid = threadIdx.x, wid = tid >> 6, lane = tid & 63;
    const int lin = blockIdx.y * 512 + blockIdx.x;        // dispatch-linear
    const int xcd = lin & 7, j = lin >> 3;
    const int bcol = (xcd * 64 + (j & 63)) * 128;
    const int brow = (j >> 6) * 128;
    const int bl = lane & 15, gk = lane >> 4;
    const int colbase = bcol + wid * 32;

    f32x4 acc[8][2] = {};
    for (int s = 0; s < 4; ++s) {
        const int koff = s * 32 + gk * 8;
        bf16x8 af[8];
        #pragma unroll
        for (int m = 0; m < 8; ++m)
            af[m] = *reinterpret_cast<const bf16x8*>(qbf + (size_t)(brow + m * 16 + bl) * D_ + koff);
        #pragma unroll
        for (int n = 0; n < 2; ++n) {
            const bf16x8 bfrag = *reinterpret_cast<const bf16x8*>(
                Bt + (size_t)(colbase + n * 16 + bl) * D_ + koff);
            #pragma unroll
            for (int m = 0; m < 8; ++m)
                acc[m][n] = __builtin_amdgcn_mfma_f32_16x16x32_bf16(af[m], bfrag, acc[m][n], 0, 0, 0);
        }
    }

    // C/D: col = lane&15, row = (lane>>4)*4 + r
    #pragma unroll
    for (int m = 0; m < 8; ++m)
        #pragma unroll
        for (int n = 0; n < 2; ++n)
            #pragma unroll
            for (int r = 0; r < 4; ++r) {
                const int orow = brow + m * 16 + (gk << 2) + r;
                logits[(size_t)orow * LROW + 1 + colbase + n * 16 + bl] = acc[m][n][r];
            }
}

// ---- proto GEMM: logits_proto = qbf @ protos^T (10/T folded into qbf) ----
__global__ __launch_bounds__(256) void gemm_proto(const __bf16* __restrict__ qbf,
                                                  const float* __restrict__ protos,
                                                  float* __restrict__ out) {
    const int wid  = threadIdx.x >> 6;
    const int lane = threadIdx.x & 63;
    const int mrow = (blockIdx.y * 4 + wid) * 16;
    const int ncol = blockIdx.x * 16;
    const int bl = lane & 15, gk = lane >> 4;
    const int col = ncol + bl;
    const bool valid = (col < C_);

    f32x4 acc = {};
    #pragma unroll
    for (int s = 0; s < 4; ++s) {
        const int koff = s * 32 + gk * 8;
        const bf16x8 a = *reinterpret_cast<const bf16x8*>(qbf + (size_t)(mrow + bl) * D_ + koff);
        bf16x8 b;
        if (valid) {
            const float* bp = protos + (size_t)col * D_ + koff;
            #pragma unroll
            for (int v = 0; v < 8; ++v) b[v] = (__bf16)bp[v];
        } else {
            #pragma unroll
            for (int v = 0; v < 8; ++v) b[v] = (__bf16)0.0f;
        }
        acc = __builtin_amdgcn_mfma_f32_16x16x32_bf16(a, b, acc, 0, 0, 0);
    }
    #pragma unroll
    for (int r = 0; r < 4; ++r) {
        const int orow = mrow + gk * 4 + r;
        if (valid) out[(size_t)orow * C_ + col] = acc[r];
    }
}

// ---- kT_patch: new_queue[d][c] = k[c][d] for c < 1024 ----
__global__ __launch_bounds__(256) void kT_patch(const float* __restrict__ k,
                                                float* __restrict__ outq) {
    __shared__ float Lf[128][129];
    const int tid = threadIdx.x;
    const int c0  = blockIdx.x * 128;
    #pragma unroll
    for (int it = 0; it < 16; ++it) {
        const int idx = it * 256 + tid;
        const int c   = idx >> 5;
        const int dq  = (idx & 31) * 4;
        const float4 v = *reinterpret_cast<const float4*>(k + (size_t)(c0 + c) * D_ + dq);
        Lf[dq + 0][c] = v.x; Lf[dq + 1][c] = v.y; Lf[dq + 2][c] = v.z; Lf[dq + 3][c] = v.w;
    }
    __syncthreads();
    #pragma unroll
    for (int it = 0; it < 16; ++it) {
        const int idx = it * 256 + tid;
        const int d   = idx >> 5;
        const int cq  = (idx & 31) * 4;
        float4 v;
        v.x = Lf[d][cq + 0]; v.y = Lf[d][cq + 1]; v.z = Lf[d][cq + 2]; v.w = Lf[d][cq + 3];
        *reinterpret_cast<float4*>(outq + (size_t)d * K_ + c0 + cq) = v;
    }
}

// ---- new_prototypes: single-pass EMA (m^cnt*(p + 0.001*sum m^-occ q)), l2norm ----
__global__ __launch_bounds__(128) void proto_update(const float* __restrict__ protos,
                                                    const float* __restrict__ q,
                                                    const int* __restrict__ target,
                                                    float* __restrict__ outp) {
    __shared__ int   t[B_];
    __shared__ float red[2];
    const int c = blockIdx.x, d = threadIdx.x;
    for (int i = d; i < B_; i += 128) t[i] = target[i];
    __syncthreads();

    float acc = 0.0f, wgt = 1.0f;
    int cnt = 0;
    for (int i = 0; i < B_; ++i) {
        if (t[i] == c) {                 // wave-uniform (LDS broadcast)
            ++cnt;
            wgt *= 1.0010010010010010f;  // 1/0.999 -> m^(-occ_i)
            acc = fmaf(wgt, q[(size_t)i * D_ + d], acc);
        }
    }
    const float val = powf(0.999f, (float)cnt) *
                      fmaf(0.001f, acc, protos[(size_t)c * D_ + d]);

    float ss = val * val;
    #pragma unroll
    for (int off = 32; off > 0; off >>= 1) ss += __shfl_xor(ss, off);
    if ((d & 63) == 0) red[d >> 6] = ss;
    __syncthreads();
    const float norm = sqrtf(red[0] + red[1]);
    outp[(size_t)c * D_ + d] = val / fmaxf(norm, 1e-12f);
}

extern "C" void kernel_launch(void* const* d_in, const int* in_sizes, int n_in,
                              void* d_out, int out_size, void* d_ws, size_t ws_size,
                              hipStream_t stream) {
    const float* q      = (const float*)d_in[0];
    const float* k      = (const float*)d_in[1];
    const float* queue  = (const float*)d_in[2];
    const float* protos = (const float*)d_in[3];
    const int*   target = (const int*)d_in[4];

    float* out    = (float*)d_out;
    float* logits = out;                                  // [1024][65537]
    float* lproto = out + (size_t)B_ * LROW;              // [1024][1000]
    float* outq   = lproto + (size_t)B_ * C_;             // [128][65536]
    float* outp   = outq + (size_t)D_ * K_;               // [1000][128]

    __bf16* Bt  = (__bf16*)d_ws;                          // [65536][128]
    __bf16* qbf = (__bf16*)((char*)d_ws + (size_t)K_ * D_ * 2);  // [1024][128]

    convert_T   <<<K_ / 128, 256, 0, stream>>>(queue, outq, Bt);
    lpos_qbf    <<<B_ / 4, 256, 0, stream>>>(q, k, logits, qbf);
    gemm_neg    <<<dim3(512, 8), 256, 0, stream>>>(qbf, Bt, logits);
    gemm_proto  <<<dim3((C_ + 15) / 16, B_ / 64), 256, 0, stream>>>(qbf, protos, lproto);
    kT_patch    <<<B_ / 128, 256, 0, stream>>>(k, outq);
    proto_update<<<C_, 128, 0, stream>>>(protos, q, target, outp);
}

// Round 4
// 177.530 us; speedup vs baseline: 1.1625x; 1.1625x over previous
//
#include <hip/hip_runtime.h>
#include <hip/hip_bf16.h>

typedef __bf16 bf16x8 __attribute__((ext_vector_type(8)));
typedef float  f32x4  __attribute__((ext_vector_type(4)));

// Sizes: q [1024][128] f32, k [1024][128] f32, queue [128][65536] f32,
//        prototypes [1000][128] f32, target [1024] int32
// Outputs (concat f32): logits [1024][65537], logits_proto [1024][1000],
//        new_queue [128][65536], new_prototypes [1000][128]
// d_ws: Bt = bf16 queue^T [65536][128], qbf = bf16(10*q) [1024][128]

#define B_   1024
#define D_   128
#define K_   65536
#define C_   1000
#define LROW 65537
#define TINV 10.0f

// ---- convert_T: read queue once; emit new_queue copy + bf16 transposed Bt ----
__global__ __launch_bounds__(256) void convert_T(const float* __restrict__ queue,
                                                 float* __restrict__ outq,
                                                 __bf16* __restrict__ Bt) {
    __shared__ __bf16 Lt[128 * 128];
    char* ltb = (char*)Lt;
    const int tid = threadIdx.x;
    const int c0  = blockIdx.x * 128;
    #pragma unroll
    for (int it = 0; it < 16; ++it) {
        const int idx = it * 256 + tid;          // float4 slot in 128d x 128c tile
        const int d   = idx >> 5;
        const int cq  = (idx & 31) * 4;
        const float4 v = *reinterpret_cast<const float4*>(queue + (size_t)d * K_ + c0 + cq);
        *reinterpret_cast<float4*>(outq + (size_t)d * K_ + c0 + cq) = v;
        const int db = d >> 3, de = (d & 7) * 2;
        float vv[4] = {v.x, v.y, v.z, v.w};
        #pragma unroll
        for (int jj = 0; jj < 4; ++jj) {
            const int c = cq + jj;
            *reinterpret_cast<__bf16*>(ltb + c * 256 + ((db ^ ((c >> 2) & 15)) << 4) + de)
                = (__bf16)vv[jj];
        }
    }
    __syncthreads();
    #pragma unroll
    for (int it = 0; it < 8; ++it) {
        const int idx = it * 256 + tid;          // 16B chunk: c = idx>>4, db = idx&15
        const int c   = idx >> 4;
        const int db  = idx & 15;
        const bf16x8 v = *reinterpret_cast<const bf16x8*>(
            ltb + c * 256 + ((db ^ ((c >> 2) & 15)) << 4));
        *reinterpret_cast<bf16x8*>(Bt + (size_t)(c0 + c) * D_ + db * 8) = v;
    }
}

// ---- l_pos + qbf: logits[:,0] = (q·k)/T ; qbf = bf16(10*q) ----
__global__ __launch_bounds__(256) void lpos_qbf(const float* __restrict__ q,
                                                const float* __restrict__ k,
                                                float* __restrict__ logits,
                                                __bf16* __restrict__ qbf) {
    const int wid  = threadIdx.x >> 6;
    const int lane = threadIdx.x & 63;
    const int row  = blockIdx.x * 4 + wid;
    const float2 qv = reinterpret_cast<const float2*>(q + (size_t)row * D_)[lane];
    const float2 kv = reinterpret_cast<const float2*>(k + (size_t)row * D_)[lane];
    union { __bf16 h[2]; unsigned int u; } t;
    t.h[0] = (__bf16)(qv.x * TINV);
    t.h[1] = (__bf16)(qv.y * TINV);
    reinterpret_cast<unsigned int*>(qbf)[row * 64 + lane] = t.u;
    float p = qv.x * kv.x + qv.y * kv.y;
    #pragma unroll
    for (int off = 32; off > 0; off >>= 1) p += __shfl_xor(p, off);
    if (lane == 0) logits[(size_t)row * LROW] = p * TINV;
}

// ---- big GEMM: logits[:,1:] = qbf @ Bt^T (10/T folded into qbf) ----
// LDS-staged A (R1 structure), SWAPPED mfma -> lane owns 4 consecutive cols,
// epilogue stores imm-folded. XCD-bijective, row-fastest within xcd (R1 order).
__global__ __launch_bounds__(256) void gemm_neg(const __bf16* __restrict__ qbf,
                                                const __bf16* __restrict__ Bt,
                                                float* __restrict__ logits) {
    __shared__ __bf16 Alds[128][128];            // 16B block cb of row r at cb^(r&7)
    const int tid = threadIdx.x, wid = tid >> 6, lane = tid & 63;
    const int lin = blockIdx.y * 512 + blockIdx.x;
    const int xcd = lin & 7, j = lin >> 3;
    const int bcol = (xcd * 64 + (j >> 3)) * 128;
    const int brow = (j & 7) * 128;

    // stage A from qbf (already bf16, already *10): 32KB, 8 iters x 16B/thread
    #pragma unroll
    for (int it = 0; it < 8; ++it) {
        const int idx = it * 256 + tid;          // 16B-block slot 0..2047
        const int r   = idx >> 4;
        const int cb  = idx & 15;
        const bf16x8 v = *reinterpret_cast<const bf16x8*>(qbf + (size_t)(brow + r) * D_ + cb * 8);
        *reinterpret_cast<bf16x8*>(&Alds[r][(cb ^ (r & 7)) * 8]) = v;
    }
    __syncthreads();

    const int bl = lane & 15, gk = lane >> 4;
    const int colbase = bcol + wid * 32;

    f32x4 acc[8][2] = {};
    #pragma unroll
    for (int s = 0; s < 4; ++s) {
        const int koff = s * 32 + gk * 8;
        bf16x8 af[8];
        #pragma unroll
        for (int m = 0; m < 8; ++m) {
            const int r = m * 16 + bl;
            af[m] = *reinterpret_cast<const bf16x8*>(&Alds[r][((s * 4 + gk) ^ (r & 7)) * 8]);
        }
        #pragma unroll
        for (int n = 0; n < 2; ++n) {
            const bf16x8 bfrag = *reinterpret_cast<const bf16x8*>(
                Bt + (size_t)(colbase + n * 16 + bl) * D_ + koff);
            #pragma unroll
            for (int m = 0; m < 8; ++m)
                acc[m][n] = __builtin_amdgcn_mfma_f32_16x16x32_bf16(bfrag, af[m], acc[m][n], 0, 0, 0);
        }
    }

    // swapped C/D: q-row-in-tile = lane&15, queue-col-in-tile = gk*4 + r
    #pragma unroll
    for (int m = 0; m < 8; ++m) {
        float* base = logits + (size_t)(brow + m * 16 + bl) * LROW + 1 + colbase + gk * 4;
        #pragma unroll
        for (int n = 0; n < 2; ++n)
            #pragma unroll
            for (int r = 0; r < 4; ++r)
                base[n * 16 + r] = acc[m][n][r];   // imm offsets 0..12, 64..76 B
    }
}

// ---- proto GEMM (swapped): logits_proto = qbf @ protos^T, aligned float4 out ----
__global__ __launch_bounds__(256) void gemm_proto(const __bf16* __restrict__ qbf,
                                                  const float* __restrict__ protos,
                                                  float* __restrict__ out) {
    const int wid  = threadIdx.x >> 6;
    const int lane = threadIdx.x & 63;
    const int mrow = (blockIdx.y * 4 + wid) * 16;   // q rows
    const int ncol = blockIdx.x * 16;               // classes
    const int bl = lane & 15, gk = lane >> 4;
    const int cls = ncol + bl;
    const bool valid = (cls < C_);

    f32x4 acc = {};
    #pragma unroll
    for (int s = 0; s < 4; ++s) {
        const int koff = s * 32 + gk * 8;
        const bf16x8 a = *reinterpret_cast<const bf16x8*>(qbf + (size_t)(mrow + bl) * D_ + koff);
        bf16x8 b;
        if (valid) {
            const float* bp = protos + (size_t)cls * D_ + koff;
            #pragma unroll
            for (int v = 0; v < 8; ++v) b[v] = (__bf16)bp[v];
        } else {
            #pragma unroll
            for (int v = 0; v < 8; ++v) b[v] = (__bf16)0.0f;
        }
        acc = __builtin_amdgcn_mfma_f32_16x16x32_bf16(b, a, acc, 0, 0, 0);
    }
    // D: q-row = mrow + bl, class = ncol + gk*4 + r
    const int qrow = mrow + bl;
    const int c0   = ncol + gk * 4;
    if (c0 + 3 < C_) {
        float4 v; v.x = acc[0]; v.y = acc[1]; v.z = acc[2]; v.w = acc[3];
        *reinterpret_cast<float4*>(out + (size_t)qrow * C_ + c0) = v;   // 16B-aligned
    } else {
        #pragma unroll
        for (int r = 0; r < 4; ++r)
            if (c0 + r < C_) out[(size_t)qrow * C_ + c0 + r] = acc[r];
    }
}

// ---- kT_patch: new_queue[d][c] = k[c][d] for c < 1024 ----
__global__ __launch_bounds__(256) void kT_patch(const float* __restrict__ k,
                                                float* __restrict__ outq) {
    __shared__ float Lf[128][129];
    const int tid = threadIdx.x;
    const int c0  = blockIdx.x * 128;
    #pragma unroll
    for (int it = 0; it < 16; ++it) {
        const int idx = it * 256 + tid;
        const int c   = idx >> 5;
        const int dq  = (idx & 31) * 4;
        const float4 v = *reinterpret_cast<const float4*>(k + (size_t)(c0 + c) * D_ + dq);
        Lf[dq + 0][c] = v.x; Lf[dq + 1][c] = v.y; Lf[dq + 2][c] = v.z; Lf[dq + 3][c] = v.w;
    }
    __syncthreads();
    #pragma unroll
    for (int it = 0; it < 16; ++it) {
        const int idx = it * 256 + tid;
        const int d   = idx >> 5;
        const int cq  = (idx & 31) * 4;
        float4 v;
        v.x = Lf[d][cq + 0]; v.y = Lf[d][cq + 1]; v.z = Lf[d][cq + 2]; v.w = Lf[d][cq + 3];
        *reinterpret_cast<float4*>(outq + (size_t)d * K_ + c0 + cq) = v;
    }
}

// ---- new_prototypes: single-pass EMA (m^cnt*(p + 0.001*sum m^-occ q)), l2norm ----
__global__ __launch_bounds__(128) void proto_update(const float* __restrict__ protos,
                                                    const float* __restrict__ q,
                                                    const int* __restrict__ target,
                                                    float* __restrict__ outp) {
    __shared__ int   t[B_];
    __shared__ float red[2];
    const int c = blockIdx.x, d = threadIdx.x;
    for (int i = d; i < B_; i += 128) t[i] = target[i];
    __syncthreads();

    float acc = 0.0f, wgt = 1.0f;
    int cnt = 0;
    for (int i = 0; i < B_; ++i) {
        if (t[i] == c) {                 // wave-uniform (LDS broadcast)
            ++cnt;
            wgt *= 1.0010010010010010f;  // 1/0.999 -> m^(-occ_i)
            acc = fmaf(wgt, q[(size_t)i * D_ + d], acc);
        }
    }
    const float val = powf(0.999f, (float)cnt) *
                      fmaf(0.001f, acc, protos[(size_t)c * D_ + d]);

    float ss = val * val;
    #pragma unroll
    for (int off = 32; off > 0; off >>= 1) ss += __shfl_xor(ss, off);
    if ((d & 63) == 0) red[d >> 6] = ss;
    __syncthreads();
    const float norm = sqrtf(red[0] + red[1]);
    outp[(size_t)c * D_ + d] = val / fmaxf(norm, 1e-12f);
}

extern "C" void kernel_launch(void* const* d_in, const int* in_sizes, int n_in,
                              void* d_out, int out_size, void* d_ws, size_t ws_size,
                              hipStream_t stream) {
    const float* q      = (const float*)d_in[0];
    const float* k      = (const float*)d_in[1];
    const float* queue  = (const float*)d_in[2];
    const float* protos = (const float*)d_in[3];
    const int*   target = (const int*)d_in[4];

    float* out    = (float*)d_out;
    float* logits = out;                                  // [1024][65537]
    float* lproto = out + (size_t)B_ * LROW;              // [1024][1000]
    float* outq   = lproto + (size_t)B_ * C_;             // [128][65536]
    float* outp   = outq + (size_t)D_ * K_;               // [1000][128]

    __bf16* Bt  = (__bf16*)d_ws;                          // [65536][128]
    __bf16* qbf = (__bf16*)((char*)d_ws + (size_t)K_ * D_ * 2);  // [1024][128]

    lpos_qbf    <<<B_ / 4, 256, 0, stream>>>(q, k, logits, qbf);
    convert_T   <<<K_ / 128, 256, 0, stream>>>(queue, outq, Bt);
    gemm_neg    <<<dim3(512, 8), 256, 0, stream>>>(qbf, Bt, logits);
    gemm_proto  <<<dim3((C_ + 15) / 16, B_ / 64), 256, 0, stream>>>(qbf, protos, lproto);
    kT_patch    <<<B_ / 128, 256, 0, stream>>>(k, outq);
    proto_update<<<C_, 128, 0, stream>>>(protos, q, target, outp);
}

// Round 5
// 160.130 us; speedup vs baseline: 1.2888x; 1.1087x over previous
//
#include <hip/hip_runtime.h>
#include <hip/hip_bf16.h>

typedef __bf16 bf16x8 __attribute__((ext_vector_type(8)));
typedef float  f32x4  __attribute__((ext_vector_type(4)));

// Sizes: q [1024][128] f32, k [1024][128] f32, queue [128][65536] f32,
//        prototypes [1000][128] f32, target [1024] int32
// Outputs (concat f32): logits [1024][65537], logits_proto [1024][1000],
//        new_queue [128][65536], new_prototypes [1000][128]
// d_ws: Bt = bf16 queue^T [65536][128], qbf = bf16(10*q) [1024][128]

#define B_   1024
#define D_   128
#define K_   65536
#define C_   1000
#define LROW 65537
#define TINV 10.0f

// ---- convert_T: read queue once; emit new_queue copy + bf16 transposed Bt ----
__global__ __launch_bounds__(256) void convert_T(const float* __restrict__ queue,
                                                 float* __restrict__ outq,
                                                 __bf16* __restrict__ Bt) {
    __shared__ __bf16 Lt[128 * 128];
    char* ltb = (char*)Lt;
    const int tid = threadIdx.x;
    const int c0  = blockIdx.x * 128;
    #pragma unroll
    for (int it = 0; it < 16; ++it) {
        const int idx = it * 256 + tid;          // float4 slot in 128d x 128c tile
        const int d   = idx >> 5;
        const int cq  = (idx & 31) * 4;
        const float4 v = *reinterpret_cast<const float4*>(queue + (size_t)d * K_ + c0 + cq);
        *reinterpret_cast<float4*>(outq + (size_t)d * K_ + c0 + cq) = v;
        const int db = d >> 3, de = (d & 7) * 2;
        float vv[4] = {v.x, v.y, v.z, v.w};
        #pragma unroll
        for (int jj = 0; jj < 4; ++jj) {
            const int c = cq + jj;
            *reinterpret_cast<__bf16*>(ltb + c * 256 + ((db ^ ((c >> 2) & 15)) << 4) + de)
                = (__bf16)vv[jj];
        }
    }
    __syncthreads();
    #pragma unroll
    for (int it = 0; it < 8; ++it) {
        const int idx = it * 256 + tid;          // 16B chunk: c = idx>>4, db = idx&15
        const int c   = idx >> 4;
        const int db  = idx & 15;
        const bf16x8 v = *reinterpret_cast<const bf16x8*>(
            ltb + c * 256 + ((db ^ ((c >> 2) & 15)) << 4));
        *reinterpret_cast<bf16x8*>(Bt + (size_t)(c0 + c) * D_ + db * 8) = v;
    }
}

// ---- misc_fused: lpos+qbf | gemm_proto | proto_update | kT, by blockIdx ----
#define MB_LPOS   256
#define MB_PROTO  1008   // grid (63,16) linearized: bx = pid%63, by = pid/63
#define MB_PUPD   500    // 2 classes per block
#define MB_KT     8
__global__ __launch_bounds__(256) void misc_fused(const float* __restrict__ q,
                                                  const float* __restrict__ k,
                                                  const float* __restrict__ protos,
                                                  const int* __restrict__ target,
                                                  float* __restrict__ logits,
                                                  __bf16* __restrict__ qbf,
                                                  float* __restrict__ lproto,
                                                  float* __restrict__ outq,
                                                  float* __restrict__ outp) {
    __shared__ int   t[B_];
    __shared__ float red[2][2];
    const int bid = blockIdx.x;
    const int tid = threadIdx.x;

    if (bid < MB_LPOS) {
        // ---- l_pos + qbf ----
        const int wid  = tid >> 6;
        const int lane = tid & 63;
        const int row  = bid * 4 + wid;
        const float2 qv = reinterpret_cast<const float2*>(q + (size_t)row * D_)[lane];
        const float2 kv = reinterpret_cast<const float2*>(k + (size_t)row * D_)[lane];
        union { __bf16 h[2]; unsigned int u; } u2;
        u2.h[0] = (__bf16)(qv.x * TINV);
        u2.h[1] = (__bf16)(qv.y * TINV);
        reinterpret_cast<unsigned int*>(qbf)[row * 64 + lane] = u2.u;
        float p = qv.x * kv.x + qv.y * kv.y;
        #pragma unroll
        for (int off = 32; off > 0; off >>= 1) p += __shfl_xor(p, off);
        if (lane == 0) logits[(size_t)row * LROW] = p * TINV;

    } else if (bid < MB_LPOS + MB_PROTO) {
        // ---- gemm_proto: lproto = (10*q) @ protos^T ----
        const int pid  = bid - MB_LPOS;
        const int bx   = pid % 63, by = pid / 63;
        const int wid  = tid >> 6;
        const int lane = tid & 63;
        const int mrow = (by * 4 + wid) * 16;
        const int ncol = bx * 16;
        const int bl = lane & 15, gk = lane >> 4;
        const int col = ncol + bl;
        const bool valid = (col < C_);

        f32x4 acc = {};
        #pragma unroll
        for (int s = 0; s < 4; ++s) {
            const int koff = s * 32 + gk * 8;
            const float* ap = q + (size_t)(mrow + bl) * D_ + koff;
            bf16x8 a, b;
            #pragma unroll
            for (int v = 0; v < 8; ++v) a[v] = (__bf16)(ap[v] * TINV);
            if (valid) {
                const float* bp = protos + (size_t)col * D_ + koff;
                #pragma unroll
                for (int v = 0; v < 8; ++v) b[v] = (__bf16)bp[v];
            } else {
                #pragma unroll
                for (int v = 0; v < 8; ++v) b[v] = (__bf16)0.0f;
            }
            acc = __builtin_amdgcn_mfma_f32_16x16x32_bf16(a, b, acc, 0, 0, 0);
        }
        #pragma unroll
        for (int r = 0; r < 4; ++r) {
            const int orow = mrow + gk * 4 + r;
            if (valid) lproto[(size_t)orow * C_ + col] = acc[r];
        }

    } else if (bid < MB_LPOS + MB_PROTO + MB_PUPD) {
        // ---- proto_update: 2 classes per block ----
        const int pid = bid - (MB_LPOS + MB_PROTO);
        const int sub = tid >> 7;          // 0/1
        const int d   = tid & 127;
        const int c   = pid * 2 + sub;     // < 1000
        for (int i = tid; i < B_; i += 256) t[i] = target[i];
        __syncthreads();

        float acc = 0.0f, wgt = 1.0f;
        int cnt = 0;
        for (int i = 0; i < B_; ++i) {
            if (t[i] == c) {                 // wave-uniform (LDS broadcast)
                ++cnt;
                wgt *= 1.0010010010010010f;  // 1/0.999 -> m^(-occ_i)
                acc = fmaf(wgt, q[(size_t)i * D_ + d], acc);
            }
        }
        const float val = powf(0.999f, (float)cnt) *
                          fmaf(0.001f, acc, protos[(size_t)c * D_ + d]);

        float ss = val * val;
        #pragma unroll
        for (int off = 32; off > 0; off >>= 1) ss += __shfl_xor(ss, off);
        if ((d & 63) == 0) red[sub][d >> 6] = ss;
        __syncthreads();
        const float norm = sqrtf(red[sub][0] + red[sub][1]);
        outp[(size_t)c * D_ + d] = val / fmaxf(norm, 1e-12f);

    } else {
        // ---- kT: new_queue[d][c] = k[c][d] for c < 1024 (LDS-free) ----
        const int pid  = bid - (MB_LPOS + MB_PROTO + MB_PUPD);   // 0..7
        const int d    = tid & 127;
        const int half = tid >> 7;
        for (int cc = 0; cc < 16; ++cc) {
            const int c4 = (pid * 32 + half * 16 + cc) * 4;
            float4 v;
            v.x = k[(size_t)(c4 + 0) * D_ + d];   // coalesced across lanes (d)
            v.y = k[(size_t)(c4 + 1) * D_ + d];
            v.z = k[(size_t)(c4 + 2) * D_ + d];
            v.w = k[(size_t)(c4 + 3) * D_ + d];
            *reinterpret_cast<float4*>(outq + (size_t)d * K_ + c4) = v;  // L2 merges
        }
    }
}

// ---- big GEMM: logits[:,1:] = qbf @ Bt^T (10/T folded into qbf) ----
// R2 orientation (non-swapped, col=bl stores) + R4 qbf staging + XOR swizzle.
__global__ __launch_bounds__(256) void gemm_neg(const __bf16* __restrict__ qbf,
                                                const __bf16* __restrict__ Bt,
                                                float* __restrict__ logits) {
    __shared__ __bf16 Alds[128][128];            // 16B block cb of row r at cb^(r&7)
    const int tid = threadIdx.x, wid = tid >> 6, lane = tid & 63;
    const int lin = blockIdx.y * 512 + blockIdx.x;
    const int xcd = lin & 7, j = lin >> 3;
    const int bcol = (xcd * 64 + (j >> 3)) * 128;
    const int brow = (j & 7) * 128;

    #pragma unroll
    for (int it = 0; it < 8; ++it) {
        const int idx = it * 256 + tid;          // 16B-block slot 0..2047
        const int r   = idx >> 4;
        const int cb  = idx & 15;
        const bf16x8 v = *reinterpret_cast<const bf16x8*>(qbf + (size_t)(brow + r) * D_ + cb * 8);
        *reinterpret_cast<bf16x8*>(&Alds[r][(cb ^ (r & 7)) * 8]) = v;
    }
    __syncthreads();

    const int bl = lane & 15, gk = lane >> 4;
    const int colbase = bcol + wid * 32;

    f32x4 acc[8][2] = {};
    #pragma unroll
    for (int s = 0; s < 4; ++s) {
        const int koff = s * 32 + gk * 8;
        bf16x8 af[8];
        #pragma unroll
        for (int m = 0; m < 8; ++m) {
            const int r = m * 16 + bl;
            af[m] = *reinterpret_cast<const bf16x8*>(&Alds[r][((s * 4 + gk) ^ (r & 7)) * 8]);
        }
        #pragma unroll
        for (int n = 0; n < 2; ++n) {
            const bf16x8 bfrag = *reinterpret_cast<const bf16x8*>(
                Bt + (size_t)(colbase + n * 16 + bl) * D_ + koff);
            #pragma unroll
            for (int m = 0; m < 8; ++m)
                acc[m][n] = __builtin_amdgcn_mfma_f32_16x16x32_bf16(af[m], bfrag, acc[m][n], 0, 0, 0);
        }
    }

    // C/D: col = lane&15, row = (lane>>4)*4 + r
    #pragma unroll
    for (int m = 0; m < 8; ++m)
        #pragma unroll
        for (int n = 0; n < 2; ++n)
            #pragma unroll
            for (int r = 0; r < 4; ++r) {
                const int orow = brow + m * 16 + (gk << 2) + r;
                logits[(size_t)orow * LROW + 1 + colbase + n * 16 + bl] = acc[m][n][r];
            }
}

extern "C" void kernel_launch(void* const* d_in, const int* in_sizes, int n_in,
                              void* d_out, int out_size, void* d_ws, size_t ws_size,
                              hipStream_t stream) {
    const float* q      = (const float*)d_in[0];
    const float* k      = (const float*)d_in[1];
    const float* queue  = (const float*)d_in[2];
    const float* protos = (const float*)d_in[3];
    const int*   target = (const int*)d_in[4];

    float* out    = (float*)d_out;
    float* logits = out;                                  // [1024][65537]
    float* lproto = out + (size_t)B_ * LROW;              // [1024][1000]
    float* outq   = lproto + (size_t)B_ * C_;             // [128][65536]
    float* outp   = outq + (size_t)D_ * K_;               // [1000][128]

    __bf16* Bt  = (__bf16*)d_ws;                          // [65536][128]
    __bf16* qbf = (__bf16*)((char*)d_ws + (size_t)K_ * D_ * 2);  // [1024][128]

    convert_T <<<K_ / 128, 256, 0, stream>>>(queue, outq, Bt);
    misc_fused<<<MB_LPOS + MB_PROTO + MB_PUPD + MB_KT, 256, 0, stream>>>(
        q, k, protos, target, logits, qbf, lproto, outq, outp);
    gemm_neg  <<<dim3(512, 8), 256, 0, stream>>>(qbf, Bt, logits);
}